// Round 15
// baseline (139.489 us; speedup 1.0000x reference)
//
#include <hip/hip_runtime.h>

#define HM_B 32
#define HM_C 98
#define HM_H 128
#define HM_W 128
#define HWSZ (HM_H * HM_W)          // 16384
#define FDIM 256
#define DDIM 128
#define NODE_F (2 + 1 + FDIM)       // 259
#define NODE_P 260                  // padded LDS row stride
#define BC (HM_B * HM_C)            // 3136
#define HM_ELEMS ((size_t)BC * HWSZ)
#define LCHUNK 8                    // landmarks per embed block (392 blocks)
#define ICHUNK 7                    // rows per gcn block (448 blocks)
#define NTHR 256
#define NWAVE (NTHR / 64)           // 4 waves per block
#define COPY_BLOCKS 2048

typedef float f32x4 __attribute__((ext_vector_type(4)));

// Kernel 1a: READ-ONLY argmax pass. Temporal loads stream hm through L3
// (205.5 MB < 256 MB Infinity Cache -> hm stays resident for k1b).
// Wave butterfly + one 8B partial per wave. No stores in the hot path.
__global__ __launch_bounds__(NTHR) void k1a_argmax(
    const float* __restrict__ hm, float* __restrict__ pconf,
    int* __restrict__ pidx) {
    const int row = blockIdx.x;
    const int tid = threadIdx.x;
    const f32x4* __restrict__ src = (const f32x4*)(hm + (size_t)row * HWSZ);

    // issue all 16 loads back-to-back; consume in order (incremental vmcnt)
    f32x4 v[16];
    #pragma unroll
    for (int t = 0; t < 16; ++t)
        v[t] = src[t * NTHR + tid];

    float bv = -INFINITY;
    int bi = 0;
    #pragma unroll
    for (int t = 0; t < 16; ++t) {
        const f32x4 x = v[t];
        const int base = (t * NTHR + tid) * 4;
        const float m4 = fmaxf(fmaxf(x[0], x[1]), fmaxf(x[2], x[3]));
        if (m4 > bv) {  // in-order scan keeps first occurrence per thread
            if (x[0] > bv) { bv = x[0]; bi = base; }
            if (x[1] > bv) { bv = x[1]; bi = base + 1; }
            if (x[2] > bv) { bv = x[2]; bi = base + 2; }
            if (x[3] > bv) { bv = x[3]; bi = base + 3; }
        }
    }

    // wave butterfly: (max value, min index on tie) is associative
    #pragma unroll
    for (int s = 1; s < 64; s <<= 1) {
        const float ov = __shfl_xor(bv, s, 64);
        const int oi = __shfl_xor(bi, s, 64);
        if (ov > bv || (ov == bv && oi < bi)) { bv = ov; bi = oi; }
    }
    if ((tid & 63) == 0) {               // one 8B partial per wave, L2-resident
        pconf[row * NWAVE + (tid >> 6)] = bv;
        pidx[row * NWAVE + (tid >> 6)] = bi;
    }
}

// Kernel 1b: copy pass. Plain (temporal) loads — hm is L3-resident from k1a,
// so reads come from Infinity Cache; NT stores stream to HBM without
// write-allocate. Expected write-limited (~205 MB at HBM write BW).
__global__ __launch_bounds__(NTHR) void k1b_copy(
    const float* __restrict__ hm, float* __restrict__ out_hm) {
    const size_t stride = (size_t)COPY_BLOCKS * NTHR;
    const f32x4* __restrict__ src = (const f32x4*)hm;
    f32x4* __restrict__ dst = (f32x4*)out_hm;
    for (size_t p = (size_t)blockIdx.x * NTHR + threadIdx.x;
         p < HM_ELEMS / 4; p += stride) {
        __builtin_nontemporal_store(src[p], dst + p);
    }
}

// Kernel 2: combine wave partials, 8-way-MLP feature gather, embed.
// h0[bc,d] = relu(node . W_embed[:,d] + b_embed[d])
__global__ __launch_bounds__(NTHR) void k2_embed(
    const float* __restrict__ feat, const float* __restrict__ pconf,
    const int* __restrict__ pidx, const float* __restrict__ W_embed,
    const float* __restrict__ b_embed, float* __restrict__ h0_ws) {
    const int bc0 = blockIdx.x * LCHUNK;
    const int tid = threadIdx.x;
    __shared__ float node_s[LCHUNK][NODE_P];   // 8*260*4 = 8320 B
    __shared__ int locs[LCHUNK];

    if (tid < LCHUNK) {
        const int row = bc0 + tid;
        float fv = pconf[row * NWAVE];
        int fi = pidx[row * NWAVE];
        #pragma unroll
        for (int w = 1; w < NWAVE; ++w) {
            const float ov = pconf[row * NWAVE + w];
            const int oi = pidx[row * NWAVE + w];
            if (ov > fv || (ov == fv && oi < fi)) { fv = ov; fi = oi; }
        }
        locs[tid] = fi;
        node_s[tid][0] = (float)(fi % HM_W) * (1.0f / (float)HM_H);  // ref: [xs,ys]/[H,W]
        node_s[tid][1] = (float)(fi / HM_W) * (1.0f / (float)HM_W);
        node_s[tid][2] = fv;
    }
    __syncthreads();

    // gather: 8 independent scattered 64B-line NT loads per thread (8-way MLP)
    float g[LCHUNK];
    #pragma unroll
    for (int l = 0; l < LCHUNK; ++l) {
        const int bb = (bc0 + l) / HM_C;
        g[l] = __builtin_nontemporal_load(
            feat + ((size_t)(bb * FDIM + tid)) * HWSZ + locs[l]);
    }
    #pragma unroll
    for (int l = 0; l < LCHUNK; ++l)
        node_s[l][3 + tid] = g[l];
    __syncthreads();

    const int d = tid & (DDIM - 1);
    const int lbase = (tid >> 7) * 4;
    const float bias = b_embed[d];
    float a0 = bias, a1 = bias, a2 = bias, a3 = bias;
    for (int f = 0; f < NODE_F; ++f) {
        const float w = W_embed[f * DDIM + d];
        a0 = fmaf(node_s[lbase + 0][f], w, a0);
        a1 = fmaf(node_s[lbase + 1][f], w, a1);
        a2 = fmaf(node_s[lbase + 2][f], w, a2);
        a3 = fmaf(node_s[lbase + 3][f], w, a3);
    }
    h0_ws[(size_t)(bc0 + lbase + 0) * DDIM + d] = fmaxf(a0, 0.f);
    h0_ws[(size_t)(bc0 + lbase + 1) * DDIM + d] = fmaxf(a1, 0.f);
    h0_ws[(size_t)(bc0 + lbase + 2) * DDIM + d] = fmaxf(a2, 0.f);
    h0_ws[(size_t)(bc0 + lbase + 3) * DDIM + d] = fmaxf(a3, 0.f);
}

// Kernel 3: h1 = relu((A @ h0) @ W_gcn); out2 = h1 @ W_out + b_out.
__global__ __launch_bounds__(DDIM) void k3_gcn(
    const float* __restrict__ A, const float* __restrict__ h0_ws,
    const float* __restrict__ W_gcn, const float* __restrict__ W_out,
    const float* __restrict__ b_out, float* __restrict__ out2) {
    const int b = blockIdx.x / (HM_C / ICHUNK);
    const int i0 = (blockIdx.x % (HM_C / ICHUNK)) * ICHUNK;
    const int tid = threadIdx.x;           // = d

    __shared__ float arow[ICHUNK * HM_C];  // 2744 B
    __shared__ float tmp_s[ICHUNK * DDIM]; // 3584 B
    __shared__ float h1_s[ICHUNK * DDIM];  // 3584 B

    for (int k = tid; k < ICHUNK * HM_C; k += DDIM)
        arow[k] = A[(i0 + k / HM_C) * HM_C + (k % HM_C)];
    __syncthreads();

    {
        float acc[ICHUNK];
        #pragma unroll
        for (int i = 0; i < ICHUNK; ++i) acc[i] = 0.f;
        for (int j = 0; j < HM_C; ++j) {
            const float v = h0_ws[((size_t)b * HM_C + j) * DDIM + tid];
            #pragma unroll
            for (int i = 0; i < ICHUNK; ++i)
                acc[i] = fmaf(arow[i * HM_C + j], v, acc[i]);
        }
        #pragma unroll
        for (int i = 0; i < ICHUNK; ++i) tmp_s[i * DDIM + tid] = acc[i];
    }
    __syncthreads();

    {
        float acc[ICHUNK];
        #pragma unroll
        for (int i = 0; i < ICHUNK; ++i) acc[i] = 0.f;
        for (int k = 0; k < DDIM; ++k) {
            const float w = W_gcn[k * DDIM + tid];
            #pragma unroll
            for (int i = 0; i < ICHUNK; ++i)
                acc[i] = fmaf(tmp_s[i * DDIM + k], w, acc[i]);
        }
        #pragma unroll
        for (int i = 0; i < ICHUNK; ++i) h1_s[i * DDIM + tid] = fmaxf(acc[i], 0.f);
    }
    __syncthreads();

    if (tid < ICHUNK * 2) {
        const int i = tid >> 1;
        const int o = tid & 1;
        float acc = b_out[o];
        for (int dd = 0; dd < DDIM; ++dd)
            acc = fmaf(h1_s[i * DDIM + dd], W_out[dd * 2 + o], acc);
        out2[((size_t)b * HM_C + i0 + i) * 2 + o] = acc;
    }
}

extern "C" void kernel_launch(void* const* d_in, const int* in_sizes, int n_in,
                              void* d_out, int out_size, void* d_ws, size_t ws_size,
                              hipStream_t stream) {
    const float* hm      = (const float*)d_in[0];
    const float* feat    = (const float*)d_in[1];
    const float* W_embed = (const float*)d_in[2];
    const float* b_embed = (const float*)d_in[3];
    const float* A       = (const float*)d_in[4];
    const float* W_gcn   = (const float*)d_in[5];
    const float* W_out   = (const float*)d_in[6];
    const float* b_out   = (const float*)d_in[7];

    float* out_hm = (float*)d_out;                 // [B,C,H,W] passthrough
    float* out2   = (float*)d_out + HM_ELEMS;      // [B,C,2]

    char* ws = (char*)d_ws;
    float* pconf = (float*)ws;  ws += BC * NWAVE * sizeof(float);  // 50 KB
    int*   pidx  = (int*)ws;    ws += BC * NWAVE * sizeof(int);    // 50 KB
    float* h0_ws = (float*)ws;  // BC*128*4 = 1.606 MB; total ~1.7 MB

    k1a_argmax<<<BC, NTHR, 0, stream>>>(hm, pconf, pidx);
    k1b_copy<<<COPY_BLOCKS, NTHR, 0, stream>>>(hm, out_hm);
    k2_embed<<<BC / LCHUNK, NTHR, 0, stream>>>(feat, pconf, pidx,
                                               W_embed, b_embed, h0_ws);
    k3_gcn<<<HM_B * (HM_C / ICHUNK), DDIM, 0, stream>>>(A, h0_ws, W_gcn,
                                                        W_out, b_out, out2);
}

// Round 16
// 108.895 us; speedup vs baseline: 1.2809x; 1.2809x over previous
//
#include <hip/hip_runtime.h>

#define HM_B 32
#define HM_C 98
#define HM_H 128
#define HM_W 128
#define HWSZ (HM_H * HM_W)          // 16384
#define HALF (HWSZ / 2)             // 8192 floats per half-row block
#define FDIM 256
#define DDIM 128
#define NODE_F (2 + 1 + FDIM)       // 259
#define NODE_P 260                  // padded LDS row stride
#define BC (HM_B * HM_C)            // 3136
#define HM_ELEMS ((size_t)BC * HWSZ)
#define LCHUNK 8                    // landmarks per embed block (392 blocks)
#define ICHUNK 7                    // rows per gcn block (448 blocks)
#define NTHR 256
#define NWAVE (NTHR / 64)           // 4 waves per block
#define PPROW (2 * NWAVE)           // 8 partials per row (2 half-row blocks)

typedef float f32x4 __attribute__((ext_vector_type(4)));

// Kernel 1: half-row streamlined stream+argmax. 6272 blocks (2/row), 256 thr,
// 8 f32x4/thread. Depth-4 pipelined copy (temporal loads, NT stores, proven),
// wave shfl butterfly, one 8B partial per wave. No LDS, no barrier, no tail.
// vs R14 (single variable): half-row granularity -> 24.5 generations/CU,
// halving tail-generation idle and per-generation store-drain bubbles.
__global__ __launch_bounds__(NTHR) void k1_copy_argmax(
    const float* __restrict__ hm, float* __restrict__ out_hm,
    float* __restrict__ pconf, int* __restrict__ pidx) {
    const int bid = blockIdx.x;
    const int row = bid >> 1;
    const int half = bid & 1;
    const int tid = threadIdx.x;
    const size_t base = (size_t)row * HWSZ + (size_t)half * HALF;
    const f32x4* __restrict__ src = (const f32x4*)(hm + base);
    f32x4* __restrict__ dst = (f32x4*)(out_hm + base);

    float bv = -INFINITY;
    int bi = 0;
    f32x4 cur0 = src[0 * NTHR + tid];
    f32x4 cur1 = src[1 * NTHR + tid];
    f32x4 cur2 = src[2 * NTHR + tid];
    f32x4 cur3 = src[3 * NTHR + tid];
    #pragma unroll
    for (int g = 0; g < 2; ++g) {
        f32x4 nxt0, nxt1, nxt2, nxt3;
        if (g < 1) {                      // compile-time after unroll
            nxt0 = src[4 * NTHR + tid];
            nxt1 = src[5 * NTHR + tid];
            nxt2 = src[6 * NTHR + tid];
            nxt3 = src[7 * NTHR + tid];
        }
        #pragma unroll
        for (int u = 0; u < 4; ++u) {
            const f32x4 v = (u == 0) ? cur0 : (u == 1) ? cur1 : (u == 2) ? cur2 : cur3;
            const int p = (g * 4 + u) * NTHR + tid;
            __builtin_nontemporal_store(v, dst + p);
            const float m4 = fmaxf(fmaxf(v[0], v[1]), fmaxf(v[2], v[3]));
            if (m4 > bv) {  // in-order scan keeps first occurrence per thread
                const int gbase = half * HALF + p * 4;   // row-local index
                if (v[0] > bv) { bv = v[0]; bi = gbase; }
                if (v[1] > bv) { bv = v[1]; bi = gbase + 1; }
                if (v[2] > bv) { bv = v[2]; bi = gbase + 2; }
                if (v[3] > bv) { bv = v[3]; bi = gbase + 3; }
            }
        }
        cur0 = nxt0; cur1 = nxt1; cur2 = nxt2; cur3 = nxt3;
    }

    // wave butterfly: (max value, min index on tie) is associative
    #pragma unroll
    for (int s = 1; s < 64; s <<= 1) {
        const float ov = __shfl_xor(bv, s, 64);
        const int oi = __shfl_xor(bi, s, 64);
        if (ov > bv || (ov == bv && oi < bi)) { bv = ov; bi = oi; }
    }
    if ((tid & 63) == 0) {               // one 8B partial per wave, L2-resident
        const int slot = row * PPROW + half * NWAVE + (tid >> 6);
        pconf[slot] = bv;
        pidx[slot] = bi;
    }
}

// Kernel 2: combine the 8 partials/row (half-0 slots precede half-1 slots and
// hold smaller indices, so (max, min-idx-on-tie) scan preserves first occ.),
// 8-way-MLP feature gather, embed: h0 = relu(node @ W_embed + b_embed).
__global__ __launch_bounds__(NTHR) void k2_embed(
    const float* __restrict__ feat, const float* __restrict__ pconf,
    const int* __restrict__ pidx, const float* __restrict__ W_embed,
    const float* __restrict__ b_embed, float* __restrict__ h0_ws) {
    const int bc0 = blockIdx.x * LCHUNK;
    const int tid = threadIdx.x;
    __shared__ float node_s[LCHUNK][NODE_P];   // 8*260*4 = 8320 B
    __shared__ int locs[LCHUNK];

    if (tid < LCHUNK) {
        const int row = bc0 + tid;
        float fv = pconf[row * PPROW];
        int fi = pidx[row * PPROW];
        #pragma unroll
        for (int w = 1; w < PPROW; ++w) {
            const float ov = pconf[row * PPROW + w];
            const int oi = pidx[row * PPROW + w];
            if (ov > fv || (ov == fv && oi < fi)) { fv = ov; fi = oi; }
        }
        locs[tid] = fi;
        node_s[tid][0] = (float)(fi % HM_W) * (1.0f / (float)HM_H);  // ref: [xs,ys]/[H,W]
        node_s[tid][1] = (float)(fi / HM_W) * (1.0f / (float)HM_W);
        node_s[tid][2] = fv;
    }
    __syncthreads();

    // gather: 8 independent scattered 64B-line NT loads per thread (8-way MLP)
    float g[LCHUNK];
    #pragma unroll
    for (int l = 0; l < LCHUNK; ++l) {
        const int bb = (bc0 + l) / HM_C;
        g[l] = __builtin_nontemporal_load(
            feat + ((size_t)(bb * FDIM + tid)) * HWSZ + locs[l]);
    }
    #pragma unroll
    for (int l = 0; l < LCHUNK; ++l)
        node_s[l][3 + tid] = g[l];
    __syncthreads();

    const int d = tid & (DDIM - 1);
    const int lbase = (tid >> 7) * 4;
    const float bias = b_embed[d];
    float a0 = bias, a1 = bias, a2 = bias, a3 = bias;
    for (int f = 0; f < NODE_F; ++f) {
        const float w = W_embed[f * DDIM + d];
        a0 = fmaf(node_s[lbase + 0][f], w, a0);
        a1 = fmaf(node_s[lbase + 1][f], w, a1);
        a2 = fmaf(node_s[lbase + 2][f], w, a2);
        a3 = fmaf(node_s[lbase + 3][f], w, a3);
    }
    h0_ws[(size_t)(bc0 + lbase + 0) * DDIM + d] = fmaxf(a0, 0.f);
    h0_ws[(size_t)(bc0 + lbase + 1) * DDIM + d] = fmaxf(a1, 0.f);
    h0_ws[(size_t)(bc0 + lbase + 2) * DDIM + d] = fmaxf(a2, 0.f);
    h0_ws[(size_t)(bc0 + lbase + 3) * DDIM + d] = fmaxf(a3, 0.f);
}

// Kernel 3: h1 = relu((A @ h0) @ W_gcn); out2 = h1 @ W_out + b_out.
__global__ __launch_bounds__(DDIM) void k3_gcn(
    const float* __restrict__ A, const float* __restrict__ h0_ws,
    const float* __restrict__ W_gcn, const float* __restrict__ W_out,
    const float* __restrict__ b_out, float* __restrict__ out2) {
    const int b = blockIdx.x / (HM_C / ICHUNK);
    const int i0 = (blockIdx.x % (HM_C / ICHUNK)) * ICHUNK;
    const int tid = threadIdx.x;           // = d

    __shared__ float arow[ICHUNK * HM_C];  // 2744 B
    __shared__ float tmp_s[ICHUNK * DDIM]; // 3584 B
    __shared__ float h1_s[ICHUNK * DDIM];  // 3584 B

    for (int k = tid; k < ICHUNK * HM_C; k += DDIM)
        arow[k] = A[(i0 + k / HM_C) * HM_C + (k % HM_C)];
    __syncthreads();

    {
        float acc[ICHUNK];
        #pragma unroll
        for (int i = 0; i < ICHUNK; ++i) acc[i] = 0.f;
        for (int j = 0; j < HM_C; ++j) {
            const float v = h0_ws[((size_t)b * HM_C + j) * DDIM + tid];
            #pragma unroll
            for (int i = 0; i < ICHUNK; ++i)
                acc[i] = fmaf(arow[i * HM_C + j], v, acc[i]);
        }
        #pragma unroll
        for (int i = 0; i < ICHUNK; ++i) tmp_s[i * DDIM + tid] = acc[i];
    }
    __syncthreads();

    {
        float acc[ICHUNK];
        #pragma unroll
        for (int i = 0; i < ICHUNK; ++i) acc[i] = 0.f;
        for (int k = 0; k < DDIM; ++k) {
            const float w = W_gcn[k * DDIM + tid];
            #pragma unroll
            for (int i = 0; i < ICHUNK; ++i)
                acc[i] = fmaf(tmp_s[i * DDIM + k], w, acc[i]);
        }
        #pragma unroll
        for (int i = 0; i < ICHUNK; ++i) h1_s[i * DDIM + tid] = fmaxf(acc[i], 0.f);
    }
    __syncthreads();

    if (tid < ICHUNK * 2) {
        const int i = tid >> 1;
        const int o = tid & 1;
        float acc = b_out[o];
        for (int dd = 0; dd < DDIM; ++dd)
            acc = fmaf(h1_s[i * DDIM + dd], W_out[dd * 2 + o], acc);
        out2[((size_t)b * HM_C + i0 + i) * 2 + o] = acc;
    }
}

extern "C" void kernel_launch(void* const* d_in, const int* in_sizes, int n_in,
                              void* d_out, int out_size, void* d_ws, size_t ws_size,
                              hipStream_t stream) {
    const float* hm      = (const float*)d_in[0];
    const float* feat    = (const float*)d_in[1];
    const float* W_embed = (const float*)d_in[2];
    const float* b_embed = (const float*)d_in[3];
    const float* A       = (const float*)d_in[4];
    const float* W_gcn   = (const float*)d_in[5];
    const float* W_out   = (const float*)d_in[6];
    const float* b_out   = (const float*)d_in[7];

    float* out_hm = (float*)d_out;                 // [B,C,H,W] passthrough
    float* out2   = (float*)d_out + HM_ELEMS;      // [B,C,2]

    char* ws = (char*)d_ws;
    float* pconf = (float*)ws;  ws += BC * PPROW * sizeof(float);  // 100 KB
    int*   pidx  = (int*)ws;    ws += BC * PPROW * sizeof(int);    // 100 KB
    float* h0_ws = (float*)ws;  // BC*128*4 = 1.606 MB; total ~1.8 MB

    k1_copy_argmax<<<2 * BC, NTHR, 0, stream>>>(hm, out_hm, pconf, pidx);
    k2_embed<<<BC / LCHUNK, NTHR, 0, stream>>>(feat, pconf, pidx,
                                               W_embed, b_embed, h0_ws);
    k3_gcn<<<HM_B * (HM_C / ICHUNK), DDIM, 0, stream>>>(A, h0_ws, W_gcn,
                                                        W_out, b_out, out2);
}